// Round 3
// baseline (2604.922 us; speedup 1.0000x reference)
//
#include <hip/hip_runtime.h>
#include <hip/hip_bf16.h>
#include <hip/hip_fp16.h>

#define NB 8
#define NP 8192
#define NC 64
#define NM 2048
#define NK 32
#define RAD2 0.04f

typedef unsigned int u32;
typedef unsigned long long u64;
typedef _Float16 f16x8 __attribute__((ext_vector_type(8)));
typedef float f32x4 __attribute__((ext_vector_type(4)));

// exact reference arithmetic: ((dx*dx + dy*dy) + dz*dz), no FMA contraction
__device__ __forceinline__ float d2e(float ax, float ay, float az,
                                     float bx, float by, float bz) {
    float dx = __fsub_rn(ax, bx), dy = __fsub_rn(ay, by), dz = __fsub_rn(az, bz);
    return __fadd_rn(__fadd_rn(__fmul_rn(dx, dx), __fmul_rn(dy, dy)), __fmul_rn(dz, dz));
}

__device__ __forceinline__ u64 umax64(u64 a, u64 b) { return a > b ? a : b; }

// one DPP combine level for (value desc, index asc) argmax
#define RED_LEVEL(CTRL) do {                                                          \
    float v2_ = __int_as_float(__builtin_amdgcn_update_dpp(                           \
        __float_as_int(bv), __float_as_int(bv), (CTRL), 0xF, 0xF, false));            \
    int p2_ = __builtin_amdgcn_update_dpp(bp, bp, (CTRL), 0xF, 0xF, false);           \
    bool take_ = (v2_ > bv) || ((v2_ == bv) && (p2_ < bp));                           \
    bv = take_ ? v2_ : bv;                                                            \
    bp = take_ ? p2_ : bp;                                                            \
} while (0)

// ---------------- Kernel 1: farthest point sampling (1 block per cloud) ----
// 512 threads (8 waves, 2/SIMD): 16 pts/thread, p = tid + j*512.
#define FPT 16
__global__ __launch_bounds__(512, 1) void fps_kernel(const float* __restrict__ pos,
                                                     float* __restrict__ pos_s) {
    __shared__ float spos[NP * 3];
    __shared__ u64 rkey[2][8];
    const int b = blockIdx.x;
    const int tid = threadIdx.x;
    const int lane = tid & 63, wid = tid >> 6;
    const float* pb = pos + (size_t)b * (NP * 3);
    for (int i = tid; i < NP * 3; i += 512) spos[i] = pb[i];
    __syncthreads();

    float px[FPT], py[FPT], pz[FPT], mind[FPT];
    const float s0x = spos[0], s0y = spos[1], s0z = spos[2];
    float cv[2]; int cj[2];
    cv[0] = -1.0f; cv[1] = -1.0f; cj[0] = 0; cj[1] = 0;
#pragma unroll
    for (int j = 0; j < FPT; ++j) {
        int p = tid + (j << 9);
        px[j] = spos[3 * p]; py[j] = spos[3 * p + 1]; pz[j] = spos[3 * p + 2];
        float d = d2e(px[j], py[j], pz[j], s0x, s0y, s0z);
        mind[j] = d;
        int c = j >> 3;
        if (d > cv[c]) { cv[c] = d; cj[c] = j; }   // ascending j => first-max kept
    }
    float* outp = pos_s + (size_t)b * (NM * 3);
    if (tid == 0) { outp[0] = s0x; outp[1] = s0y; outp[2] = s0z; }

    for (int t = 1; t < NM; ++t) {
        // combine 2 chains: within a thread, chain0's p < chain1's p, so strict >
        // keeps the first-max tie-break
        float bv = cv[0]; int bj = cj[0];
        if (cv[1] > bv) { bv = cv[1]; bj = cj[1]; }
        int bp = tid + (bj << 9);
        // wave64 DPP argmax reduce -> lane 63 (value desc, index asc)
        RED_LEVEL(0x111);  // row_shr:1
        RED_LEVEL(0x112);  // row_shr:2
        RED_LEVEL(0x114);  // row_shr:4
        RED_LEVEL(0x118);  // row_shr:8
        RED_LEVEL(0x142);  // row_bcast:15
        RED_LEVEL(0x143);  // row_bcast:31
        float wv = __int_as_float(__builtin_amdgcn_readlane(__float_as_int(bv), 63));
        int wp = __builtin_amdgcn_readlane(bp, 63);
        u64 key = ((u64)__float_as_uint(wv) << 32) | (u32)(0xFFFFFFFFu - (u32)wp);
        if (lane == 0) rkey[t & 1][wid] = key;
        __syncthreads();
        const u64* rk = rkey[t & 1];
        u64 k0 = umax64(rk[0], rk[1]), k1 = umax64(rk[2], rk[3]);
        u64 k2 = umax64(rk[4], rk[5]), k3 = umax64(rk[6], rk[7]);
        k0 = umax64(k0, k1); k2 = umax64(k2, k3); k0 = umax64(k0, k2);
        const int nxt = (int)(0xFFFFFFFFu - (u32)k0);
        const float sx = spos[3 * nxt], sy = spos[3 * nxt + 1], sz = spos[3 * nxt + 2];
        if (tid == 0) { outp[3 * t] = sx; outp[3 * t + 1] = sy; outp[3 * t + 2] = sz; }
        cv[0] = -1.0f; cv[1] = -1.0f; cj[0] = 0; cj[1] = 0;
#pragma unroll
        for (int j = 0; j < FPT; ++j) {
            float d = d2e(px[j], py[j], pz[j], sx, sy, sz);
            float nm = fminf(mind[j], d);
            mind[j] = nm;
            int c = j >> 3;
            if (nm > cv[c]) { cv[c] = nm; cj[c] = j; }
        }
    }
}

// ---------------- Kernel 2: radius-limited 32-NN (8 queries per block) -----
#define GQ 8
#define CAP 768
__global__ __launch_bounds__(256, 1) void knn_kernel(const float* __restrict__ pos,
                                                     const float* __restrict__ pos_s,
                                                     int* __restrict__ nbr) {
    __shared__ u64 keys[GQ][CAP];
    __shared__ int cnt[GQ];
    const int qbase = blockIdx.x * GQ;
    const int b = qbase >> 11;
    const int tid = threadIdx.x;
    if (tid < GQ) cnt[tid] = 0;
    for (int i = tid; i < GQ * NK; i += 256) nbr[qbase * NK + i] = -1;

    float qx[GQ], qy[GQ], qz[GQ];
#pragma unroll
    for (int q = 0; q < GQ; ++q) {
        qx[q] = pos_s[(qbase + q) * 3];
        qy[q] = pos_s[(qbase + q) * 3 + 1];
        qz[q] = pos_s[(qbase + q) * 3 + 2];
    }
    __syncthreads();

    const float* pb = pos + (size_t)b * (NP * 3);
    for (int i = 0; i < NP / 256; ++i) {
        int p = tid + (i << 8);
        float x = pb[3 * p], y = pb[3 * p + 1], z = pb[3 * p + 2];
#pragma unroll
        for (int q = 0; q < GQ; ++q) {
            float d = d2e(x, y, z, qx[q], qy[q], qz[q]);
            if (d <= RAD2) {
                int slot = atomicAdd(&cnt[q], 1);
                if (slot < CAP) keys[q][slot] = ((u64)__float_as_uint(d) << 32) | (u32)p;
            }
        }
    }
    __syncthreads();

    // exact rank selection: keys are unique (idx in low bits) -> stable top-k
    for (int q = 0; q < GQ; ++q) {
        int c = min(cnt[q], CAP);
        for (int j = tid; j < c; j += 256) {
            u64 key = keys[q][j];
            int rank = 0;
            for (int t2 = 0; t2 < c; ++t2) rank += (keys[q][t2] < key) ? 1 : 0;
            if (rank < NK) nbr[(qbase + q) * NK + rank] = (int)(u32)(key & 0xFFFFFFFFull);
        }
    }
}

// ---------------- Kernel 3: gather + MLP (fp16 MFMA) + masked max-pool -----
#define FPAD 104
#define HPAD 72
#define TG 8
__global__ __launch_bounds__(512, 1) void mlp_kernel(
    const float* __restrict__ x, const float* __restrict__ pos,
    const float* __restrict__ W0, const float* __restrict__ b0,
    const float* __restrict__ W1, const float* __restrict__ b1,
    const float* __restrict__ W2, const float* __restrict__ b2,
    const float* __restrict__ pos_s, const int* __restrict__ nbr,
    float* __restrict__ x1) {
    __shared__ _Float16 feat[256 * FPAD];   // reused as h2[256][HPAD] after GEMM1
    __shared__ _Float16 h1[256 * HPAD];
    __shared__ _Float16 wt0[64 * FPAD];
    __shared__ _Float16 wt1[64 * HPAD];
    __shared__ _Float16 wt2[128 * HPAD];
    __shared__ float bias0[64], bias1[64], bias2[128];
    __shared__ int vld[256];

    const int tid = threadIdx.x;
    const int g0 = blockIdx.x * TG;
    const int b = g0 >> 11;

    // stage weights transposed: wt[c][j] = W[j][c], zero-padded in K
    for (int idx = tid; idx < 64 * FPAD; idx += 512) {
        int c2 = idx / FPAD, j = idx - c2 * FPAD;
        wt0[idx] = (_Float16)((j < 67) ? W0[j * 64 + c2] : 0.0f);
    }
    for (int idx = tid; idx < 64 * HPAD; idx += 512) {
        int c2 = idx / HPAD, j = idx - c2 * HPAD;
        wt1[idx] = (_Float16)((j < 64) ? W1[j * 64 + c2] : 0.0f);
    }
    for (int idx = tid; idx < 128 * HPAD; idx += 512) {
        int c2 = idx / HPAD, j = idx - c2 * HPAD;
        wt2[idx] = (_Float16)((j < 64) ? W2[j * 128 + c2] : 0.0f);
    }
    if (tid < 64) { bias0[tid] = b0[tid]; bias1[tid] = b1[tid]; }
    else if (tid < 192) bias2[tid - 64] = b2[tid - 64];

    // gather features: 2 threads per row, rows = (group, k)
    {
        int r = tid >> 1, half = tid & 1;
        int g = g0 + (r >> 5), k = r & 31;
        int nid = nbr[g * NK + k];
        int nid2 = nid < 0 ? 0 : nid;
        const float* xr = x + ((size_t)b * NP + nid2) * NC + half * 32;
        _Float16* dst = &feat[r * FPAD + half * 32];
#pragma unroll
        for (int i = 0; i < 8; ++i) {
            float4 v = *(const float4*)(xr + i * 4);
            dst[i * 4 + 0] = (_Float16)v.x; dst[i * 4 + 1] = (_Float16)v.y;
            dst[i * 4 + 2] = (_Float16)v.z; dst[i * 4 + 3] = (_Float16)v.w;
        }
        if (half) {
            const float* pj = pos + ((size_t)b * NP + nid2) * 3;
            const float* ps = pos_s + (size_t)g * 3;
            feat[r * FPAD + 64] = (_Float16)(pj[0] - ps[0]);
            feat[r * FPAD + 65] = (_Float16)(pj[1] - ps[1]);
            feat[r * FPAD + 66] = (_Float16)(pj[2] - ps[2]);
#pragma unroll
            for (int j = 67; j < 96; ++j) feat[r * FPAD + j] = (_Float16)0.0f;
        } else {
            vld[r] = (nid >= 0) ? 1 : 0;
        }
    }
    __syncthreads();

    const int lane = tid & 63, w = tid >> 6;
    const int rb = w * 32;          // this wave owns one (b,m) group = 32 rows
    const int ar = lane & 15;
    const int kg = lane >> 4;

    // GEMM1: feat[256x96] x W0 -> h1[256x64], relu
    {
        f32x4 acc[2][4] = {};
#pragma unroll
        for (int kt = 0; kt < 3; ++kt) {
            f16x8 a0 = *(const f16x8*)&feat[(rb + ar) * FPAD + kt * 32 + kg * 8];
            f16x8 a1 = *(const f16x8*)&feat[(rb + 16 + ar) * FPAD + kt * 32 + kg * 8];
#pragma unroll
            for (int nt = 0; nt < 4; ++nt) {
                f16x8 bb = *(const f16x8*)&wt0[(nt * 16 + ar) * FPAD + kt * 32 + kg * 8];
                acc[0][nt] = __builtin_amdgcn_mfma_f32_16x16x32_f16(a0, bb, acc[0][nt], 0, 0, 0);
                acc[1][nt] = __builtin_amdgcn_mfma_f32_16x16x32_f16(a1, bb, acc[1][nt], 0, 0, 0);
            }
        }
#pragma unroll
        for (int mt = 0; mt < 2; ++mt)
#pragma unroll
            for (int nt = 0; nt < 4; ++nt)
#pragma unroll
                for (int ri = 0; ri < 4; ++ri) {
                    int row = rb + mt * 16 + kg * 4 + ri;
                    int col = nt * 16 + ar;
                    float v = fmaxf(acc[mt][nt][ri] + bias0[col], 0.0f);
                    h1[row * HPAD + col] = (_Float16)v;
                }
    }
    __syncthreads();

    // GEMM2: h1[256x64] x W1 -> h2 (reusing feat), relu
    _Float16* h2 = feat;
    {
        f32x4 acc[2][4] = {};
#pragma unroll
        for (int kt = 0; kt < 2; ++kt) {
            f16x8 a0 = *(const f16x8*)&h1[(rb + ar) * HPAD + kt * 32 + kg * 8];
            f16x8 a1 = *(const f16x8*)&h1[(rb + 16 + ar) * HPAD + kt * 32 + kg * 8];
#pragma unroll
            for (int nt = 0; nt < 4; ++nt) {
                f16x8 bb = *(const f16x8*)&wt1[(nt * 16 + ar) * HPAD + kt * 32 + kg * 8];
                acc[0][nt] = __builtin_amdgcn_mfma_f32_16x16x32_f16(a0, bb, acc[0][nt], 0, 0, 0);
                acc[1][nt] = __builtin_amdgcn_mfma_f32_16x16x32_f16(a1, bb, acc[1][nt], 0, 0, 0);
            }
        }
#pragma unroll
        for (int mt = 0; mt < 2; ++mt)
#pragma unroll
            for (int nt = 0; nt < 4; ++nt)
#pragma unroll
                for (int ri = 0; ri < 4; ++ri) {
                    int row = rb + mt * 16 + kg * 4 + ri;
                    int col = nt * 16 + ar;
                    float v = fmaxf(acc[mt][nt][ri] + bias1[col], 0.0f);
                    h2[row * HPAD + col] = (_Float16)v;
                }
    }
    __syncthreads();

    // GEMM3: h2[256x64] x W2 -> [256x128], relu + masked max-pool over k=32
    {
        f32x4 acc[2][8] = {};
#pragma unroll
        for (int kt = 0; kt < 2; ++kt) {
            f16x8 a0 = *(const f16x8*)&h2[(rb + ar) * HPAD + kt * 32 + kg * 8];
            f16x8 a1 = *(const f16x8*)&h2[(rb + 16 + ar) * HPAD + kt * 32 + kg * 8];
#pragma unroll
            for (int nt = 0; nt < 8; ++nt) {
                f16x8 bb = *(const f16x8*)&wt2[(nt * 16 + ar) * HPAD + kt * 32 + kg * 8];
                acc[0][nt] = __builtin_amdgcn_mfma_f32_16x16x32_f16(a0, bb, acc[0][nt], 0, 0, 0);
                acc[1][nt] = __builtin_amdgcn_mfma_f32_16x16x32_f16(a1, bb, acc[1][nt], 0, 0, 0);
            }
        }
        const int g = g0 + w;
#pragma unroll
        for (int nt = 0; nt < 8; ++nt) {
            int col = nt * 16 + ar;
            float bz = bias2[col];
            float bmax = 0.0f;   // h>=0 post-relu and self is always valid
#pragma unroll
            for (int mt = 0; mt < 2; ++mt)
#pragma unroll
                for (int ri = 0; ri < 4; ++ri) {
                    int row = rb + mt * 16 + kg * 4 + ri;
                    float v = fmaxf(acc[mt][nt][ri] + bz, 0.0f);
                    bmax = fmaxf(bmax, vld[row] ? v : 0.0f);
                }
            bmax = fmaxf(bmax, __shfl_xor(bmax, 16));
            bmax = fmaxf(bmax, __shfl_xor(bmax, 32));
            if (lane < 16) x1[(size_t)g * 128 + nt * 16 + lane] = bmax;
        }
    }
}

extern "C" void kernel_launch(void* const* d_in, const int* in_sizes, int n_in,
                              void* d_out, int out_size, void* d_ws, size_t ws_size,
                              hipStream_t stream) {
    const float* x   = (const float*)d_in[0];
    const float* pos = (const float*)d_in[1];
    const float* W0  = (const float*)d_in[2];
    const float* b0  = (const float*)d_in[3];
    const float* W1  = (const float*)d_in[4];
    const float* b1  = (const float*)d_in[5];
    const float* W2  = (const float*)d_in[6];
    const float* b2  = (const float*)d_in[7];
    float* x1    = (float*)d_out;
    float* pos_s = x1 + (size_t)NB * NM * 128;   // outputs concatenated: x1 then pos_s
    int* nbr = (int*)d_ws;                        // [NB*NM, NK] int32 = 2MB

    fps_kernel<<<NB, 512, 0, stream>>>(pos, pos_s);
    knn_kernel<<<(NB * NM) / GQ, 256, 0, stream>>>(pos, pos_s, nbr);
    mlp_kernel<<<(NB * NM) / TG, 512, 0, stream>>>(x, pos, W0, b0, W1, b1, W2, b2,
                                                   pos_s, nbr, x1);
}

// Round 4
// 1855.909 us; speedup vs baseline: 1.4036x; 1.4036x over previous
//
#include <hip/hip_runtime.h>
#include <hip/hip_bf16.h>
#include <hip/hip_fp16.h>

#define NB 8
#define NP 8192
#define NC 64
#define NM 2048
#define NK 32
#define RAD2 0.04f

typedef unsigned int u32;
typedef unsigned long long u64;
typedef _Float16 f16x8 __attribute__((ext_vector_type(8)));
typedef float f32x4 __attribute__((ext_vector_type(4)));

// exact reference arithmetic: ((dx*dx + dy*dy) + dz*dz), no FMA contraction
__device__ __forceinline__ float d2e(float ax, float ay, float az,
                                     float bx, float by, float bz) {
    float dx = __fsub_rn(ax, bx), dy = __fsub_rn(ay, by), dz = __fsub_rn(az, bz);
    return __fadd_rn(__fadd_rn(__fmul_rn(dx, dx), __fmul_rn(dy, dy)), __fmul_rn(dz, dz));
}

__device__ __forceinline__ int spread3(int v) {
    return (v & 1) | ((v & 2) << 2) | ((v & 4) << 4);
}

// one DPP combine level of u64 max (keys unique -> strict > is exact)
#define RED64(CTRL) do {                                                              \
    u32 hi_ = (u32)(k >> 32), lo_ = (u32)k;                                           \
    u32 h2_ = (u32)__builtin_amdgcn_update_dpp((int)hi_, (int)hi_, (CTRL), 0xF, 0xF, false); \
    u32 l2_ = (u32)__builtin_amdgcn_update_dpp((int)lo_, (int)lo_, (CTRL), 0xF, 0xF, false); \
    u64 o_ = ((u64)h2_ << 32) | l2_;                                                  \
    if (o_ > k) k = o_;                                                               \
} while (0)

// ---------------- Kernel 1: farthest point sampling (1 block per cloud) ----
// 512 threads x 16 pts. Morton-sorted cells + certified per-thread skip.
#define FPT 16
__global__ __launch_bounds__(512, 1) void fps_kernel(const float* __restrict__ pos,
                                                     float* __restrict__ pos_s) {
    __shared__ float ssx[NP], ssy[NP], ssz[NP];
    __shared__ u32 ssid[NP];
    __shared__ u32 hist[512], cursor[512];
    __shared__ u64 gkey[3];
    __shared__ u32 pos0srt;

    const int b = blockIdx.x;
    const int tid = threadIdx.x;
    const int lane = tid & 63;
    const float* pb = pos + (size_t)b * (NP * 3);

    // ---- phase A: load my 16 points (48 contiguous floats), morton keys ----
    float ax[FPT], ay[FPT], az[FPT];
    int key[FPT];
    {
        float f[48];
        const float4* src = (const float4*)(pb + tid * 48);
#pragma unroll
        for (int v = 0; v < 12; ++v) *(float4*)&f[v * 4] = src[v];
#pragma unroll
        for (int j = 0; j < FPT; ++j) {
            ax[j] = f[3 * j]; ay[j] = f[3 * j + 1]; az[j] = f[3 * j + 2];
            int qx = min(7, max(0, (int)(ax[j] * 8.0f)));
            int qy = min(7, max(0, (int)(ay[j] * 8.0f)));
            int qz = min(7, max(0, (int)(az[j] * 8.0f)));
            key[j] = (spread3(qx) << 2) | (spread3(qy) << 1) | spread3(qz);
        }
    }
    hist[tid] = 0;
    __syncthreads();
#pragma unroll
    for (int j = 0; j < FPT; ++j) atomicAdd(&hist[key[j]], 1);
    __syncthreads();
    // inclusive scan over 512 bins (Hillis-Steele)
    for (int off = 1; off < 512; off <<= 1) {
        u32 v = (tid >= off) ? hist[tid - off] : 0;
        __syncthreads();
        hist[tid] += v;
        __syncthreads();
    }
    cursor[tid] = (tid == 0) ? 0u : hist[tid - 1];
    if (tid == 0) { gkey[0] = 0; gkey[1] = 0; gkey[2] = 0; }
    __syncthreads();
    // ---- phase B: scatter into morton order ----
#pragma unroll
    for (int j = 0; j < FPT; ++j) {
        int dst = (int)atomicAdd(&cursor[key[j]], 1);
        ssx[dst] = ax[j]; ssy[dst] = ay[j]; ssz[dst] = az[j];
        u32 orig = tid * FPT + j;
        ssid[dst] = orig;
        if (orig == 0) pos0srt = (u32)dst;
    }
    __syncthreads();

    // ---- phase C: register-load my sorted range, bbox, init vs point 0 ----
    const int base = tid * FPT;
    const u32 p0 = pos0srt;
    const float s0x = ssx[p0], s0y = ssy[p0], s0z = ssz[p0];
    float px[FPT], py[FPT], pz[FPT];
    u64 mkey[FPT];
    float lox, hix, loy, hiy, loz, hiz;
#pragma unroll
    for (int j = 0; j < FPT; ++j) {
        px[j] = ssx[base + j]; py[j] = ssy[base + j]; pz[j] = ssz[base + j];
        u32 sid = ssid[base + j];
        float d = d2e(px[j], py[j], pz[j], s0x, s0y, s0z);
        u32 lo = ((8191u - sid) << 13) | (u32)(base + j);
        mkey[j] = ((u64)__float_as_uint(d) << 32) | lo;
        if (j == 0) {
            lox = hix = px[0]; loy = hiy = py[0]; loz = hiz = pz[0];
        } else {
            lox = fminf(lox, px[j]); hix = fmaxf(hix, px[j]);
            loy = fminf(loy, py[j]); hiy = fmaxf(hiy, py[j]);
            loz = fminf(loz, pz[j]); hiz = fmaxf(hiz, pz[j]);
        }
    }
    float* outp = pos_s + (size_t)b * (NM * 3);
    if (tid == 0) { outp[0] = s0x; outp[1] = s0y; outp[2] = s0z; }
    u64 ck = mkey[0];
#pragma unroll
    for (int j = 1; j < FPT; ++j) ck = (mkey[j] > ck) ? mkey[j] : ck;

    // ---- main loop: one barrier per iteration ----
    int slot = 1, prv = 0;
    for (int t = 1; t < NM; ++t) {
        u64 k = ck;
        RED64(0x111);  // row_shr:1
        RED64(0x112);  // row_shr:2
        RED64(0x114);  // row_shr:4
        RED64(0x118);  // row_shr:8
        RED64(0x142);  // row_bcast:15
        RED64(0x143);  // row_bcast:31
        if (lane == 63) atomicMax(&gkey[slot], k);
        __syncthreads();
        u64 gk = gkey[slot];
        if (tid == 0) gkey[prv] = 0;   // 3-slot rotation: race-free reset
        const int srt = (int)(gk & 0x1FFFu);
        const float sx = ssx[srt], sy = ssy[srt], sz = ssz[srt];
        if (tid == 0) { outp[3 * t] = sx; outp[3 * t + 1] = sy; outp[3 * t + 2] = sz; }
        // certified skip: minDist^2(bbox,s)*(1-1e-6) >= max mind in cell
        float gx = fmaxf(fmaxf(__fsub_rn(lox, sx), __fsub_rn(sx, hix)), 0.0f);
        float gy = fmaxf(fmaxf(__fsub_rn(loy, sy), __fsub_rn(sy, hiy)), 0.0f);
        float gz = fmaxf(fmaxf(__fsub_rn(loz, sz), __fsub_rn(sz, hiz)), 0.0f);
        float bnd = gx * gx + gy * gy + gz * gz;
        float cvf = __uint_as_float((u32)(ck >> 32));
        if (bnd * 0.999999f < cvf) {
            u64 nk = 0;
#pragma unroll
            for (int j = 0; j < FPT; ++j) {
                float d = d2e(px[j], py[j], pz[j], sx, sy, sz);
                u32 hi = min((u32)(mkey[j] >> 32), __float_as_uint(d));
                u64 nm = ((u64)hi << 32) | (u32)mkey[j];
                mkey[j] = nm;
                nk = (j == 0) ? nm : ((nm > nk) ? nm : nk);
            }
            ck = nk;
        }
        prv = slot; slot = (slot == 2) ? 0 : slot + 1;
    }
}

// ---------------- Kernel 2: radius-limited 32-NN (8 queries per block) -----
#define GQ 8
#define CAP 768
__global__ __launch_bounds__(256, 1) void knn_kernel(const float* __restrict__ pos,
                                                     const float* __restrict__ pos_s,
                                                     int* __restrict__ nbr) {
    __shared__ u64 keys[GQ][CAP];
    __shared__ int cnt[GQ];
    const int qbase = blockIdx.x * GQ;
    const int b = qbase >> 11;
    const int tid = threadIdx.x;
    if (tid < GQ) cnt[tid] = 0;
    for (int i = tid; i < GQ * NK; i += 256) nbr[qbase * NK + i] = -1;

    float qx[GQ], qy[GQ], qz[GQ];
#pragma unroll
    for (int q = 0; q < GQ; ++q) {
        qx[q] = pos_s[(qbase + q) * 3];
        qy[q] = pos_s[(qbase + q) * 3 + 1];
        qz[q] = pos_s[(qbase + q) * 3 + 2];
    }
    __syncthreads();

    const float* pb = pos + (size_t)b * (NP * 3);
    for (int i = 0; i < NP / 256; ++i) {
        int p = tid + (i << 8);
        float x = pb[3 * p], y = pb[3 * p + 1], z = pb[3 * p + 2];
#pragma unroll
        for (int q = 0; q < GQ; ++q) {
            float d = d2e(x, y, z, qx[q], qy[q], qz[q]);
            if (d <= RAD2) {
                int slot = atomicAdd(&cnt[q], 1);
                if (slot < CAP) keys[q][slot] = ((u64)__float_as_uint(d) << 32) | (u32)p;
            }
        }
    }
    __syncthreads();

    // exact rank selection: keys are unique (idx in low bits) -> stable top-k
    for (int q = 0; q < GQ; ++q) {
        int c = min(cnt[q], CAP);
        for (int j = tid; j < c; j += 256) {
            u64 key = keys[q][j];
            int rank = 0;
            for (int t2 = 0; t2 < c; ++t2) rank += (keys[q][t2] < key) ? 1 : 0;
            if (rank < NK) nbr[(qbase + q) * NK + rank] = (int)(u32)(key & 0xFFFFFFFFull);
        }
    }
}

// ---------------- Kernel 3: gather + MLP (fp16 MFMA) + masked max-pool -----
#define FPAD 104
#define HPAD 72
#define TG 8
__global__ __launch_bounds__(512, 1) void mlp_kernel(
    const float* __restrict__ x, const float* __restrict__ pos,
    const float* __restrict__ W0, const float* __restrict__ b0,
    const float* __restrict__ W1, const float* __restrict__ b1,
    const float* __restrict__ W2, const float* __restrict__ b2,
    const float* __restrict__ pos_s, const int* __restrict__ nbr,
    float* __restrict__ x1) {
    __shared__ _Float16 feat[256 * FPAD];   // reused as h2[256][HPAD] after GEMM1
    __shared__ _Float16 h1[256 * HPAD];
    __shared__ _Float16 wt0[64 * FPAD];
    __shared__ _Float16 wt1[64 * HPAD];
    __shared__ _Float16 wt2[128 * HPAD];
    __shared__ float bias0[64], bias1[64], bias2[128];
    __shared__ int vld[256];

    const int tid = threadIdx.x;
    const int g0 = blockIdx.x * TG;
    const int b = g0 >> 11;

    // stage weights transposed: wt[c][j] = W[j][c], zero-padded in K
    for (int idx = tid; idx < 64 * FPAD; idx += 512) {
        int c2 = idx / FPAD, j = idx - c2 * FPAD;
        wt0[idx] = (_Float16)((j < 67) ? W0[j * 64 + c2] : 0.0f);
    }
    for (int idx = tid; idx < 64 * HPAD; idx += 512) {
        int c2 = idx / HPAD, j = idx - c2 * HPAD;
        wt1[idx] = (_Float16)((j < 64) ? W1[j * 64 + c2] : 0.0f);
    }
    for (int idx = tid; idx < 128 * HPAD; idx += 512) {
        int c2 = idx / HPAD, j = idx - c2 * HPAD;
        wt2[idx] = (_Float16)((j < 64) ? W2[j * 128 + c2] : 0.0f);
    }
    if (tid < 64) { bias0[tid] = b0[tid]; bias1[tid] = b1[tid]; }
    else if (tid < 192) bias2[tid - 64] = b2[tid - 64];

    // gather features: 2 threads per row, rows = (group, k)
    {
        int r = tid >> 1, half = tid & 1;
        int g = g0 + (r >> 5), k = r & 31;
        int nid = nbr[g * NK + k];
        int nid2 = nid < 0 ? 0 : nid;
        const float* xr = x + ((size_t)b * NP + nid2) * NC + half * 32;
        _Float16* dst = &feat[r * FPAD + half * 32];
#pragma unroll
        for (int i = 0; i < 8; ++i) {
            float4 v = *(const float4*)(xr + i * 4);
            dst[i * 4 + 0] = (_Float16)v.x; dst[i * 4 + 1] = (_Float16)v.y;
            dst[i * 4 + 2] = (_Float16)v.z; dst[i * 4 + 3] = (_Float16)v.w;
        }
        if (half) {
            const float* pj = pos + ((size_t)b * NP + nid2) * 3;
            const float* ps = pos_s + (size_t)g * 3;
            feat[r * FPAD + 64] = (_Float16)(pj[0] - ps[0]);
            feat[r * FPAD + 65] = (_Float16)(pj[1] - ps[1]);
            feat[r * FPAD + 66] = (_Float16)(pj[2] - ps[2]);
#pragma unroll
            for (int j = 67; j < 96; ++j) feat[r * FPAD + j] = (_Float16)0.0f;
        } else {
            vld[r] = (nid >= 0) ? 1 : 0;
        }
    }
    __syncthreads();

    const int lane = tid & 63, w = tid >> 6;
    const int rb = w * 32;          // this wave owns one (b,m) group = 32 rows
    const int ar = lane & 15;
    const int kg = lane >> 4;

    // GEMM1: feat[256x96] x W0 -> h1[256x64], relu
    {
        f32x4 acc[2][4] = {};
#pragma unroll
        for (int kt = 0; kt < 3; ++kt) {
            f16x8 a0 = *(const f16x8*)&feat[(rb + ar) * FPAD + kt * 32 + kg * 8];
            f16x8 a1 = *(const f16x8*)&feat[(rb + 16 + ar) * FPAD + kt * 32 + kg * 8];
#pragma unroll
            for (int nt = 0; nt < 4; ++nt) {
                f16x8 bb = *(const f16x8*)&wt0[(nt * 16 + ar) * FPAD + kt * 32 + kg * 8];
                acc[0][nt] = __builtin_amdgcn_mfma_f32_16x16x32_f16(a0, bb, acc[0][nt], 0, 0, 0);
                acc[1][nt] = __builtin_amdgcn_mfma_f32_16x16x32_f16(a1, bb, acc[1][nt], 0, 0, 0);
            }
        }
#pragma unroll
        for (int mt = 0; mt < 2; ++mt)
#pragma unroll
            for (int nt = 0; nt < 4; ++nt)
#pragma unroll
                for (int ri = 0; ri < 4; ++ri) {
                    int row = rb + mt * 16 + kg * 4 + ri;
                    int col = nt * 16 + ar;
                    float v = fmaxf(acc[mt][nt][ri] + bias0[col], 0.0f);
                    h1[row * HPAD + col] = (_Float16)v;
                }
    }
    __syncthreads();

    // GEMM2: h1[256x64] x W1 -> h2 (reusing feat), relu
    _Float16* h2 = feat;
    {
        f32x4 acc[2][4] = {};
#pragma unroll
        for (int kt = 0; kt < 2; ++kt) {
            f16x8 a0 = *(const f16x8*)&h1[(rb + ar) * HPAD + kt * 32 + kg * 8];
            f16x8 a1 = *(const f16x8*)&h1[(rb + 16 + ar) * HPAD + kt * 32 + kg * 8];
#pragma unroll
            for (int nt = 0; nt < 4; ++nt) {
                f16x8 bb = *(const f16x8*)&wt1[(nt * 16 + ar) * HPAD + kt * 32 + kg * 8];
                acc[0][nt] = __builtin_amdgcn_mfma_f32_16x16x32_f16(a0, bb, acc[0][nt], 0, 0, 0);
                acc[1][nt] = __builtin_amdgcn_mfma_f32_16x16x32_f16(a1, bb, acc[1][nt], 0, 0, 0);
            }
        }
#pragma unroll
        for (int mt = 0; mt < 2; ++mt)
#pragma unroll
            for (int nt = 0; nt < 4; ++nt)
#pragma unroll
                for (int ri = 0; ri < 4; ++ri) {
                    int row = rb + mt * 16 + kg * 4 + ri;
                    int col = nt * 16 + ar;
                    float v = fmaxf(acc[mt][nt][ri] + bias1[col], 0.0f);
                    h2[row * HPAD + col] = (_Float16)v;
                }
    }
    __syncthreads();

    // GEMM3: h2[256x64] x W2 -> [256x128], relu + masked max-pool over k=32
    {
        f32x4 acc[2][8] = {};
#pragma unroll
        for (int kt = 0; kt < 2; ++kt) {
            f16x8 a0 = *(const f16x8*)&h2[(rb + ar) * HPAD + kt * 32 + kg * 8];
            f16x8 a1 = *(const f16x8*)&h2[(rb + 16 + ar) * HPAD + kt * 32 + kg * 8];
#pragma unroll
            for (int nt = 0; nt < 8; ++nt) {
                f16x8 bb = *(const f16x8*)&wt2[(nt * 16 + ar) * HPAD + kt * 32 + kg * 8];
                acc[0][nt] = __builtin_amdgcn_mfma_f32_16x16x32_f16(a0, bb, acc[0][nt], 0, 0, 0);
                acc[1][nt] = __builtin_amdgcn_mfma_f32_16x16x32_f16(a1, bb, acc[1][nt], 0, 0, 0);
            }
        }
        const int g = g0 + w;
#pragma unroll
        for (int nt = 0; nt < 8; ++nt) {
            int col = nt * 16 + ar;
            float bz = bias2[col];
            float bmax = 0.0f;   // h>=0 post-relu and self is always valid
#pragma unroll
            for (int mt = 0; mt < 2; ++mt)
#pragma unroll
                for (int ri = 0; ri < 4; ++ri) {
                    int row = rb + mt * 16 + kg * 4 + ri;
                    float v = fmaxf(acc[mt][nt][ri] + bz, 0.0f);
                    bmax = fmaxf(bmax, vld[row] ? v : 0.0f);
                }
            bmax = fmaxf(bmax, __shfl_xor(bmax, 16));
            bmax = fmaxf(bmax, __shfl_xor(bmax, 32));
            if (lane < 16) x1[(size_t)g * 128 + nt * 16 + lane] = bmax;
        }
    }
}

extern "C" void kernel_launch(void* const* d_in, const int* in_sizes, int n_in,
                              void* d_out, int out_size, void* d_ws, size_t ws_size,
                              hipStream_t stream) {
    const float* x   = (const float*)d_in[0];
    const float* pos = (const float*)d_in[1];
    const float* W0  = (const float*)d_in[2];
    const float* b0  = (const float*)d_in[3];
    const float* W1  = (const float*)d_in[4];
    const float* b1  = (const float*)d_in[5];
    const float* W2  = (const float*)d_in[6];
    const float* b2  = (const float*)d_in[7];
    float* x1    = (float*)d_out;
    float* pos_s = x1 + (size_t)NB * NM * 128;   // outputs concatenated: x1 then pos_s
    int* nbr = (int*)d_ws;                        // [NB*NM, NK] int32 = 2MB

    fps_kernel<<<NB, 512, 0, stream>>>(pos, pos_s);
    knn_kernel<<<(NB * NM) / GQ, 256, 0, stream>>>(pos, pos_s, nbr);
    mlp_kernel<<<(NB * NM) / TG, 512, 0, stream>>>(x, pos, W0, b0, W1, b1, W2, b2,
                                                   pos_s, nbr, x1);
}

// Round 5
// 1680.072 us; speedup vs baseline: 1.5505x; 1.1047x over previous
//
#include <hip/hip_runtime.h>
#include <hip/hip_bf16.h>
#include <hip/hip_fp16.h>

#define NB 8
#define NP 8192
#define NC 64
#define NM 2048
#define NK 32
#define RAD2 0.04f

typedef unsigned int u32;
typedef unsigned long long u64;
typedef _Float16 f16x8 __attribute__((ext_vector_type(8)));
typedef float f32x4 __attribute__((ext_vector_type(4)));

// exact reference arithmetic: ((dx*dx + dy*dy) + dz*dz), no FMA contraction
__device__ __forceinline__ float d2e(float ax, float ay, float az,
                                     float bx, float by, float bz) {
    float dx = __fsub_rn(ax, bx), dy = __fsub_rn(ay, by), dz = __fsub_rn(az, bz);
    return __fadd_rn(__fadd_rn(__fmul_rn(dx, dx), __fmul_rn(dy, dy)), __fmul_rn(dz, dz));
}

__device__ __forceinline__ int spread3(int v) {
    return (v & 1) | ((v & 2) << 2) | ((v & 4) << 4);
}

// one DPP combine level of u64 max (keys unique -> strict > is exact)
#define RED64(CTRL) do {                                                              \
    u32 hi_ = (u32)(k >> 32), lo_ = (u32)k;                                           \
    u32 h2_ = (u32)__builtin_amdgcn_update_dpp((int)hi_, (int)hi_, (CTRL), 0xF, 0xF, false); \
    u32 l2_ = (u32)__builtin_amdgcn_update_dpp((int)lo_, (int)lo_, (CTRL), 0xF, 0xF, false); \
    u64 o_ = ((u64)h2_ << 32) | l2_;                                                  \
    if (o_ > k) k = o_;                                                               \
} while (0)

// ---------------- Kernel 1: farthest point sampling (1 block per cloud) ----
// 1024 threads x 8 pts. Morton-sorted + certified skip + wave-key caching.
#define FPT 8
__global__ __launch_bounds__(1024, 1) void fps_kernel(const float* __restrict__ pos,
                                                      float* __restrict__ pos_s) {
    __shared__ float ssx[NP], ssy[NP], ssz[NP];
    __shared__ u32 ssid[NP];
    __shared__ u32 hist[512], cursor[512];
    __shared__ u64 gkey[3];
    __shared__ u32 pos0srt;

    const int b = blockIdx.x;
    const int tid = threadIdx.x;
    const int lane = tid & 63;
    const float* pb = pos + (size_t)b * (NP * 3);

    // ---- phase A: load my 8 points (24 contiguous floats), morton keys ----
    float ax[FPT], ay[FPT], az[FPT];
    int key[FPT];
    {
        float f[24];
        const float4* src = (const float4*)(pb + tid * 24);
#pragma unroll
        for (int v = 0; v < 6; ++v) *(float4*)&f[v * 4] = src[v];
#pragma unroll
        for (int j = 0; j < FPT; ++j) {
            ax[j] = f[3 * j]; ay[j] = f[3 * j + 1]; az[j] = f[3 * j + 2];
            int qx = min(7, max(0, (int)(ax[j] * 8.0f)));
            int qy = min(7, max(0, (int)(ay[j] * 8.0f)));
            int qz = min(7, max(0, (int)(az[j] * 8.0f)));
            key[j] = (spread3(qx) << 2) | (spread3(qy) << 1) | spread3(qz);
        }
    }
    if (tid < 512) hist[tid] = 0;
    __syncthreads();
#pragma unroll
    for (int j = 0; j < FPT; ++j) atomicAdd(&hist[key[j]], 1);
    __syncthreads();
    // inclusive scan over 512 bins (Hillis-Steele)
    for (int off = 1; off < 512; off <<= 1) {
        u32 v = 0;
        if (tid < 512 && tid >= off) v = hist[tid - off];
        __syncthreads();
        if (tid < 512) hist[tid] += v;
        __syncthreads();
    }
    if (tid < 512) cursor[tid] = (tid == 0) ? 0u : hist[tid - 1];
    if (tid == 0) { gkey[0] = 0; gkey[1] = 0; gkey[2] = 0; }
    __syncthreads();
    // ---- phase B: scatter into morton order ----
#pragma unroll
    for (int j = 0; j < FPT; ++j) {
        int dst = (int)atomicAdd(&cursor[key[j]], 1);
        ssx[dst] = ax[j]; ssy[dst] = ay[j]; ssz[dst] = az[j];
        u32 orig = tid * FPT + j;
        ssid[dst] = orig;
        if (orig == 0) pos0srt = (u32)dst;
    }
    __syncthreads();

    // ---- phase C: register-load my sorted range, bbox, init vs point 0 ----
    const int base = tid * FPT;
    const u32 p0 = pos0srt;
    const float s0x = ssx[p0], s0y = ssy[p0], s0z = ssz[p0];
    float px[FPT], py[FPT], pz[FPT];
    u64 mkey[FPT];
    float lox, hix, loy, hiy, loz, hiz;
#pragma unroll
    for (int j = 0; j < FPT; ++j) {
        px[j] = ssx[base + j]; py[j] = ssy[base + j]; pz[j] = ssz[base + j];
        u32 sid = ssid[base + j];
        float d = d2e(px[j], py[j], pz[j], s0x, s0y, s0z);
        u32 lo = ((8191u - sid) << 13) | (u32)(base + j);
        mkey[j] = ((u64)__float_as_uint(d) << 32) | lo;
        if (j == 0) {
            lox = hix = px[0]; loy = hiy = py[0]; loz = hiz = pz[0];
        } else {
            lox = fminf(lox, px[j]); hix = fmaxf(hix, px[j]);
            loy = fminf(loy, py[j]); hiy = fmaxf(hiy, py[j]);
            loz = fminf(loz, pz[j]); hiz = fmaxf(hiz, pz[j]);
        }
    }
    float* outp = pos_s + (size_t)b * (NM * 3);
    if (tid == 0) { outp[0] = s0x; outp[1] = s0y; outp[2] = s0z; }
    u64 ck = mkey[0];
#pragma unroll
    for (int j = 1; j < FPT; ++j) ck = (mkey[j] > ck) ? mkey[j] : ck;

    // ---- main loop: one barrier per iteration; reduce only if wave changed --
    bool upd = true;
    u64 wkey = 0;
    int slot = 1, prv = 0;
    for (int t = 1; t < NM; ++t) {
        if (__ballot(upd)) {
            u64 k = ck;
            RED64(0x111);  // row_shr:1
            RED64(0x112);  // row_shr:2
            RED64(0x114);  // row_shr:4
            RED64(0x118);  // row_shr:8
            RED64(0x142);  // row_bcast:15
            RED64(0x143);  // row_bcast:31
            wkey = k;
        }
        if (lane == 63) atomicMax(&gkey[slot], wkey);
        __syncthreads();
        u64 gk = gkey[slot];
        if (tid == 0) gkey[prv] = 0;   // 3-slot rotation: race-free reset
        const int srt = (int)(gk & 0x1FFFu);
        const float sx = ssx[srt], sy = ssy[srt], sz = ssz[srt];
        if (tid == 0) { outp[3 * t] = sx; outp[3 * t + 1] = sy; outp[3 * t + 2] = sz; }
        // certified skip: minDist^2(bbox,s)*(1-1e-6) >= max mind in cell
        float gx = fmaxf(fmaxf(__fsub_rn(lox, sx), __fsub_rn(sx, hix)), 0.0f);
        float gy = fmaxf(fmaxf(__fsub_rn(loy, sy), __fsub_rn(sy, hiy)), 0.0f);
        float gz = fmaxf(fmaxf(__fsub_rn(loz, sz), __fsub_rn(sz, hiz)), 0.0f);
        float bnd = gx * gx + gy * gy + gz * gz;
        float cvf = __uint_as_float((u32)(ck >> 32));
        upd = (bnd * 0.999999f < cvf);
        if (upd) {
            u64 nk = 0;
#pragma unroll
            for (int j = 0; j < FPT; ++j) {
                float d = d2e(px[j], py[j], pz[j], sx, sy, sz);
                u32 hi = min((u32)(mkey[j] >> 32), __float_as_uint(d));
                u64 nm = ((u64)hi << 32) | (u32)mkey[j];
                mkey[j] = nm;
                nk = (j == 0) ? nm : ((nm > nk) ? nm : nk);
            }
            ck = nk;
        }
        prv = slot; slot = (slot == 2) ? 0 : slot + 1;
    }
}

// ---------------- Kernel 2: radius-limited 32-NN (8 queries per block) -----
#define GQ 8
#define CAP 768
__global__ __launch_bounds__(256, 1) void knn_kernel(const float* __restrict__ pos,
                                                     const float* __restrict__ pos_s,
                                                     int* __restrict__ nbr) {
    __shared__ u64 keys[GQ][CAP];
    __shared__ int cnt[GQ];
    const int qbase = blockIdx.x * GQ;
    const int b = qbase >> 11;
    const int tid = threadIdx.x;
    if (tid < GQ) cnt[tid] = 0;
    for (int i = tid; i < GQ * NK; i += 256) nbr[qbase * NK + i] = -1;

    float qx[GQ], qy[GQ], qz[GQ];
#pragma unroll
    for (int q = 0; q < GQ; ++q) {
        qx[q] = pos_s[(qbase + q) * 3];
        qy[q] = pos_s[(qbase + q) * 3 + 1];
        qz[q] = pos_s[(qbase + q) * 3 + 2];
    }
    __syncthreads();

    const float* pb = pos + (size_t)b * (NP * 3);
    for (int i = 0; i < NP / 256; ++i) {
        int p = tid + (i << 8);
        float x = pb[3 * p], y = pb[3 * p + 1], z = pb[3 * p + 2];
#pragma unroll
        for (int q = 0; q < GQ; ++q) {
            float d = d2e(x, y, z, qx[q], qy[q], qz[q]);
            if (d <= RAD2) {
                int slot = atomicAdd(&cnt[q], 1);
                if (slot < CAP) keys[q][slot] = ((u64)__float_as_uint(d) << 32) | (u32)p;
            }
        }
    }
    __syncthreads();

    // exact rank selection: keys are unique (idx in low bits) -> stable top-k
    for (int q = 0; q < GQ; ++q) {
        int c = min(cnt[q], CAP);
        for (int j = tid; j < c; j += 256) {
            u64 key = keys[q][j];
            int rank = 0;
            for (int t2 = 0; t2 < c; ++t2) rank += (keys[q][t2] < key) ? 1 : 0;
            if (rank < NK) nbr[(qbase + q) * NK + rank] = (int)(u32)(key & 0xFFFFFFFFull);
        }
    }
}

// ---------------- Kernel 3: gather + MLP (fp16 MFMA) + masked max-pool -----
#define FPAD 104
#define HPAD 72
#define TG 8
__global__ __launch_bounds__(512, 1) void mlp_kernel(
    const float* __restrict__ x, const float* __restrict__ pos,
    const float* __restrict__ W0, const float* __restrict__ b0,
    const float* __restrict__ W1, const float* __restrict__ b1,
    const float* __restrict__ W2, const float* __restrict__ b2,
    const float* __restrict__ pos_s, const int* __restrict__ nbr,
    float* __restrict__ x1) {
    __shared__ _Float16 feat[256 * FPAD];   // reused as h2[256][HPAD] after GEMM1
    __shared__ _Float16 h1[256 * HPAD];
    __shared__ _Float16 wt0[64 * FPAD];
    __shared__ _Float16 wt1[64 * HPAD];
    __shared__ _Float16 wt2[128 * HPAD];
    __shared__ float bias0[64], bias1[64], bias2[128];
    __shared__ int vld[256];

    const int tid = threadIdx.x;
    const int g0 = blockIdx.x * TG;
    const int b = g0 >> 11;

    // stage weights transposed: wt[c][j] = W[j][c], zero-padded in K
    for (int idx = tid; idx < 64 * FPAD; idx += 512) {
        int c2 = idx / FPAD, j = idx - c2 * FPAD;
        wt0[idx] = (_Float16)((j < 67) ? W0[j * 64 + c2] : 0.0f);
    }
    for (int idx = tid; idx < 64 * HPAD; idx += 512) {
        int c2 = idx / HPAD, j = idx - c2 * HPAD;
        wt1[idx] = (_Float16)((j < 64) ? W1[j * 64 + c2] : 0.0f);
    }
    for (int idx = tid; idx < 128 * HPAD; idx += 512) {
        int c2 = idx / HPAD, j = idx - c2 * HPAD;
        wt2[idx] = (_Float16)((j < 64) ? W2[j * 128 + c2] : 0.0f);
    }
    if (tid < 64) { bias0[tid] = b0[tid]; bias1[tid] = b1[tid]; }
    else if (tid < 192) bias2[tid - 64] = b2[tid - 64];

    // gather features: 2 threads per row, rows = (group, k)
    {
        int r = tid >> 1, half = tid & 1;
        int g = g0 + (r >> 5), k = r & 31;
        int nid = nbr[g * NK + k];
        int nid2 = nid < 0 ? 0 : nid;
        const float* xr = x + ((size_t)b * NP + nid2) * NC + half * 32;
        _Float16* dst = &feat[r * FPAD + half * 32];
#pragma unroll
        for (int i = 0; i < 8; ++i) {
            float4 v = *(const float4*)(xr + i * 4);
            dst[i * 4 + 0] = (_Float16)v.x; dst[i * 4 + 1] = (_Float16)v.y;
            dst[i * 4 + 2] = (_Float16)v.z; dst[i * 4 + 3] = (_Float16)v.w;
        }
        if (half) {
            const float* pj = pos + ((size_t)b * NP + nid2) * 3;
            const float* ps = pos_s + (size_t)g * 3;
            feat[r * FPAD + 64] = (_Float16)(pj[0] - ps[0]);
            feat[r * FPAD + 65] = (_Float16)(pj[1] - ps[1]);
            feat[r * FPAD + 66] = (_Float16)(pj[2] - ps[2]);
#pragma unroll
            for (int j = 67; j < 96; ++j) feat[r * FPAD + j] = (_Float16)0.0f;
        } else {
            vld[r] = (nid >= 0) ? 1 : 0;
        }
    }
    __syncthreads();

    const int lane = tid & 63, w = tid >> 6;
    const int rb = w * 32;          // this wave owns one (b,m) group = 32 rows
    const int ar = lane & 15;
    const int kg = lane >> 4;

    // GEMM1: feat[256x96] x W0 -> h1[256x64], relu
    {
        f32x4 acc[2][4] = {};
#pragma unroll
        for (int kt = 0; kt < 3; ++kt) {
            f16x8 a0 = *(const f16x8*)&feat[(rb + ar) * FPAD + kt * 32 + kg * 8];
            f16x8 a1 = *(const f16x8*)&feat[(rb + 16 + ar) * FPAD + kt * 32 + kg * 8];
#pragma unroll
            for (int nt = 0; nt < 4; ++nt) {
                f16x8 bb = *(const f16x8*)&wt0[(nt * 16 + ar) * FPAD + kt * 32 + kg * 8];
                acc[0][nt] = __builtin_amdgcn_mfma_f32_16x16x32_f16(a0, bb, acc[0][nt], 0, 0, 0);
                acc[1][nt] = __builtin_amdgcn_mfma_f32_16x16x32_f16(a1, bb, acc[1][nt], 0, 0, 0);
            }
        }
#pragma unroll
        for (int mt = 0; mt < 2; ++mt)
#pragma unroll
            for (int nt = 0; nt < 4; ++nt)
#pragma unroll
                for (int ri = 0; ri < 4; ++ri) {
                    int row = rb + mt * 16 + kg * 4 + ri;
                    int col = nt * 16 + ar;
                    float v = fmaxf(acc[mt][nt][ri] + bias0[col], 0.0f);
                    h1[row * HPAD + col] = (_Float16)v;
                }
    }
    __syncthreads();

    // GEMM2: h1[256x64] x W1 -> h2 (reusing feat), relu
    _Float16* h2 = feat;
    {
        f32x4 acc[2][4] = {};
#pragma unroll
        for (int kt = 0; kt < 2; ++kt) {
            f16x8 a0 = *(const f16x8*)&h1[(rb + ar) * HPAD + kt * 32 + kg * 8];
            f16x8 a1 = *(const f16x8*)&h1[(rb + 16 + ar) * HPAD + kt * 32 + kg * 8];
#pragma unroll
            for (int nt = 0; nt < 4; ++nt) {
                f16x8 bb = *(const f16x8*)&wt1[(nt * 16 + ar) * HPAD + kt * 32 + kg * 8];
                acc[0][nt] = __builtin_amdgcn_mfma_f32_16x16x32_f16(a0, bb, acc[0][nt], 0, 0, 0);
                acc[1][nt] = __builtin_amdgcn_mfma_f32_16x16x32_f16(a1, bb, acc[1][nt], 0, 0, 0);
            }
        }
#pragma unroll
        for (int mt = 0; mt < 2; ++mt)
#pragma unroll
            for (int nt = 0; nt < 4; ++nt)
#pragma unroll
                for (int ri = 0; ri < 4; ++ri) {
                    int row = rb + mt * 16 + kg * 4 + ri;
                    int col = nt * 16 + ar;
                    float v = fmaxf(acc[mt][nt][ri] + bias1[col], 0.0f);
                    h2[row * HPAD + col] = (_Float16)v;
                }
    }
    __syncthreads();

    // GEMM3: h2[256x64] x W2 -> [256x128], relu + masked max-pool over k=32
    {
        f32x4 acc[2][8] = {};
#pragma unroll
        for (int kt = 0; kt < 2; ++kt) {
            f16x8 a0 = *(const f16x8*)&h2[(rb + ar) * HPAD + kt * 32 + kg * 8];
            f16x8 a1 = *(const f16x8*)&h2[(rb + 16 + ar) * HPAD + kt * 32 + kg * 8];
#pragma unroll
            for (int nt = 0; nt < 8; ++nt) {
                f16x8 bb = *(const f16x8*)&wt2[(nt * 16 + ar) * HPAD + kt * 32 + kg * 8];
                acc[0][nt] = __builtin_amdgcn_mfma_f32_16x16x32_f16(a0, bb, acc[0][nt], 0, 0, 0);
                acc[1][nt] = __builtin_amdgcn_mfma_f32_16x16x32_f16(a1, bb, acc[1][nt], 0, 0, 0);
            }
        }
        const int g = g0 + w;
#pragma unroll
        for (int nt = 0; nt < 8; ++nt) {
            int col = nt * 16 + ar;
            float bz = bias2[col];
            float bmax = 0.0f;   // h>=0 post-relu and self is always valid
#pragma unroll
            for (int mt = 0; mt < 2; ++mt)
#pragma unroll
                for (int ri = 0; ri < 4; ++ri) {
                    int row = rb + mt * 16 + kg * 4 + ri;
                    float v = fmaxf(acc[mt][nt][ri] + bz, 0.0f);
                    bmax = fmaxf(bmax, vld[row] ? v : 0.0f);
                }
            bmax = fmaxf(bmax, __shfl_xor(bmax, 16));
            bmax = fmaxf(bmax, __shfl_xor(bmax, 32));
            if (lane < 16) x1[(size_t)g * 128 + nt * 16 + lane] = bmax;
        }
    }
}

extern "C" void kernel_launch(void* const* d_in, const int* in_sizes, int n_in,
                              void* d_out, int out_size, void* d_ws, size_t ws_size,
                              hipStream_t stream) {
    const float* x   = (const float*)d_in[0];
    const float* pos = (const float*)d_in[1];
    const float* W0  = (const float*)d_in[2];
    const float* b0  = (const float*)d_in[3];
    const float* W1  = (const float*)d_in[4];
    const float* b1  = (const float*)d_in[5];
    const float* W2  = (const float*)d_in[6];
    const float* b2  = (const float*)d_in[7];
    float* x1    = (float*)d_out;
    float* pos_s = x1 + (size_t)NB * NM * 128;   // outputs concatenated: x1 then pos_s
    int* nbr = (int*)d_ws;                        // [NB*NM, NK] int32 = 2MB

    fps_kernel<<<NB, 1024, 0, stream>>>(pos, pos_s);
    knn_kernel<<<(NB * NM) / GQ, 256, 0, stream>>>(pos, pos_s, nbr);
    mlp_kernel<<<(NB * NM) / TG, 512, 0, stream>>>(x, pos, W0, b0, W1, b1, W2, b2,
                                                   pos_s, nbr, x1);
}